// Round 1
// baseline (530.481 us; speedup 1.0000x reference)
//
#include <hip/hip_runtime.h>

#define NSET 38
#define NSETP 48                       // sets padded to 4*12 for float4 addend reads
#define NSNAP 9
#define PPB 256                        // points per kA block
#define NBLK_A 256
#define PART_PER_BLK (NSNAP*NSETP*64)  // 27648 floats per block
#define PART_SZ (NBLK_A*PART_PER_BLK)  // 7,077,888 floats

// kA dynamic LDS layout (bytes):
//  zt     [256][68] f32  : 69632  @0      (+4 pad: bank-clean b128 stores & b32 col reads)
//  Wl     [64][64]  f32  : 16384  @69632
//  addend [256][48] f32  : 49152  @86016  (mask ? 0 : -1e38)
//  memb   [256]     u64  :  2048  @135168
#define KA_LDS 137216

__global__ __launch_bounds__(256, 1) void kA(
    const int* __restrict__ x, const float* __restrict__ w0,
    const float* __restrict__ cw, const float* __restrict__ cb,
    const float* __restrict__ pa, float* __restrict__ partial)
{
  extern __shared__ __align__(16) char smem[];
  float* zt = (float*)smem;
  float* Wl = (float*)(smem + 69632);
  float* addend = (float*)(smem + 86016);
  unsigned long long* memb = (unsigned long long*)(smem + 135168);

  const int tid = threadIdx.x;
  const int p = (blockIdx.x << 8) + tid;

  // membership bits for this thread's point
  unsigned long long m = 0ull;
  #pragma unroll
  for (int s = 0; s < NSET; ++s)
    m |= (unsigned long long)(x[s * 65536 + p] == 1) << s;
  memb[tid] = m;
  __syncthreads();

  // addend table: [p][set] = in-set ? 0 : -1e38 (reused across all 9 snapshots)
  #pragma unroll 1
  for (int i = tid; i < PPB * NSETP; i += 256) {
    int pp = i / NSETP;
    int j = i - pp * NSETP;
    addend[i] = (j < NSET && ((memb[pp] >> j) & 1ull)) ? 0.f : -1e38f;
  }

  // layer 0 (conv0): z = pts @ w0.T + b0
  float z[64], zn[64];
  {
    float px = -1.f + (2.f / 255.f) * (float)(p & 255);   // gx = lin[p%256]
    float py = -1.f + (2.f / 255.f) * (float)(p >> 8);    // gy = lin[p/256]
    #pragma unroll
    for (int d = 0; d < 64; ++d)
      zn[d] = fmaf(px, w0[2*d], fmaf(py, w0[2*d+1], cb[d]));
  }

  const int d0 = tid & 63;
  const int g = tid >> 6;          // set-group 0..3, 12 sets each
  float* myrow = &zt[tid * 68];

  #pragma unroll 1
  for (int s = 0; s < NSNAP; ++s) {
    // PReLU (pool in PReLU domain; monotone since a>0, conv max recovered in kB)
    #pragma unroll
    for (int d = 0; d < 64; ++d) {
      float zv = zn[d];
      z[d] = zv > 0.f ? zv : pa[(s << 6) + d] * zv;
    }
    __syncthreads();   // prior reduce reads / addend build complete
    #pragma unroll
    for (int q = 0; q < 16; ++q)
      *(float4*)&myrow[q << 2] = make_float4(z[4*q], z[4*q+1], z[4*q+2], z[4*q+3]);
    __syncthreads();   // zt ready

    // masked-max partials: thread (d0,g) pools 12 sets over the block's 256 points
    float run[12];
    #pragma unroll
    for (int j = 0; j < 12; ++j) run[j] = -3e38f;
    #pragma unroll 1
    for (int pp = 0; pp < PPB; pp += 2) {
      float v0 = zt[pp * 68 + d0];
      float v1 = zt[(pp + 1) * 68 + d0];
      const float4* a0 = (const float4*)&addend[pp * NSETP + g * 12];
      const float4* a1 = (const float4*)&addend[(pp + 1) * NSETP + g * 12];
      #pragma unroll
      for (int q = 0; q < 3; ++q) {
        float4 x0 = a0[q], x1 = a1[q];
        run[4*q+0] = fmaxf(fmaxf(run[4*q+0], v0 + x0.x), v1 + x1.x);
        run[4*q+1] = fmaxf(fmaxf(run[4*q+1], v0 + x0.y), v1 + x1.y);
        run[4*q+2] = fmaxf(fmaxf(run[4*q+2], v0 + x0.z), v1 + x1.z);
        run[4*q+3] = fmaxf(fmaxf(run[4*q+3], v0 + x0.w), v1 + x1.w);
      }
    }
    {
      float* pb = partial + (size_t)blockIdx.x * PART_PER_BLK
                + s * (NSETP * 64) + (g * 12) * 64 + d0;
      #pragma unroll
      for (int j = 0; j < 12; ++j) pb[j * 64] = run[j];
    }

    if (s < 8) {
      // stage next conv weights (safe: last Wl reads were before this iter's barriers)
      #pragma unroll
      for (int q = 0; q < 4; ++q) {
        int idx = (q << 10) + (tid << 2);
        *(float4*)&Wl[idx] = *(const float4*)&cw[(s << 12) + idx];
      }
      __syncthreads(); // Wl ready
      #pragma unroll
      for (int d = 0; d < 64; ++d) {
        float acc = cb[((s + 1) << 6) + d];
        #pragma unroll
        for (int k = 0; k < 64; k += 4) {
          float4 wv = *(const float4*)&Wl[(d << 6) + k];
          acc = fmaf(z[k],   wv.x, acc);
          acc = fmaf(z[k+1], wv.y, acc);
          acc = fmaf(z[k+2], wv.z, acc);
          acc = fmaf(z[k+3], wv.w, acc);
        }
        zn[d] = acc;
      }
    }
  }
}

// zero-point snapshots: conv-domain and prelu-domain, 9 x 64 each
__global__ void kZ(const float* __restrict__ cw, const float* __restrict__ cb,
                   const float* __restrict__ pa,
                   float* __restrict__ zsc, float* __restrict__ zsp)
{
  __shared__ float zl[64];
  int d = threadIdx.x;  // 64 threads
  float z = cb[d];      // point (0,0): conv0 out = bias
  #pragma unroll 1
  for (int s = 0; s < NSNAP; ++s) {
    zsc[(s << 6) + d] = z;
    float a = pa[(s << 6) + d];
    float zp = z > 0.f ? z : a * z;
    zsp[(s << 6) + d] = zp;
    if (s < 8) {
      __syncthreads();
      zl[d] = zp;
      __syncthreads();
      float acc = cb[((s + 1) << 6) + d];
      for (int k = 0; k < 64; ++k)
        acc = fmaf(zl[k], cw[(s << 12) + (d << 6) + k], acc);
      z = acc;
    }
  }
}

// reduce block partials -> pooled -> feat (both conv & prelu layers)
__global__ void kB(const float* __restrict__ partial, const float* __restrict__ zsc,
                   const float* __restrict__ zsp, const float* __restrict__ pa,
                   float* __restrict__ feat)
{
  int idx = blockIdx.x * 256 + threadIdx.x;
  if (idx >= NSNAP * NSET * 64) return;
  int s = idx / (NSET * 64);
  int r = idx - s * (NSET * 64);
  int set = r >> 6;
  int d = r & 63;
  float mx = -3e38f;
  const float* p0 = partial + s * (NSETP * 64) + set * 64 + d;
  #pragma unroll 4
  for (int blk = 0; blk < NBLK_A; ++blk)
    mx = fmaxf(mx, p0[(size_t)blk * PART_PER_BLK]);
  int b = set / 19, c = set - b * 19;
  float even_v, odd_v;
  if (mx < -5e37f) {                 // empty set -> zero-point snapshot
    even_v = zsc[(s << 6) + d];
    odd_v  = zsp[(s << 6) + d];
  } else {
    odd_v = mx;                      // prelu-domain max
    float a = pa[(s << 6) + d];
    even_v = mx > 0.f ? mx : mx / a; // inverse prelu -> conv-domain max
  }
  size_t fb = ((size_t)b * 18 + 2 * s) * 1216 + c * 64 + d;
  feat[fb] = even_v;
  feat[fb + 1216] = odd_v;
}

// out[b][l][s] = scale * <feat[b][17-l], fc_w[17-l][s]> + fc_b[17-l][s]
__global__ __launch_bounds__(256) void kC(const float* __restrict__ feat,
    const float* __restrict__ fcw, const float* __restrict__ fcb,
    float* __restrict__ out)
{
  __shared__ float f0[1216], f1[1216];
  int lr = blockIdx.y;          // 0..17 (original layer index)
  int chunk = blockIdx.x;       // 0..31, 16 rows each
  int tid = threadIdx.x;
  for (int i = tid; i < 1216; i += 256) {
    f0[i] = feat[(size_t)(0 * 18 + lr) * 1216 + i];
    f1[i] = feat[(size_t)(1 * 18 + lr) * 1216 + i];
  }
  __syncthreads();
  int wv = tid >> 6, lane = tid & 63;
  float scale = 1.f / sqrtf(1216.f);
  int l = 17 - lr;
  #pragma unroll 1
  for (int rr = 0; rr < 4; ++rr) {
    int srow = (chunk << 4) + (wv << 2) + rr;
    const float* wrow = fcw + ((size_t)lr * 512 + srow) * 1216;
    float pp0 = 0.f, pp1 = 0.f;
    #pragma unroll
    for (int k = 0; k < 19; ++k) {
      float w = wrow[(k << 6) + lane];
      pp0 = fmaf(w, f0[(k << 6) + lane], pp0);
      pp1 = fmaf(w, f1[(k << 6) + lane], pp1);
    }
    #pragma unroll
    for (int off = 32; off; off >>= 1) {
      pp0 += __shfl_xor(pp0, off, 64);
      pp1 += __shfl_xor(pp1, off, 64);
    }
    if (lane == 0) {
      float b = fcb[lr * 512 + srow];
      out[((size_t)0 * 18 + l) * 512 + srow] = fmaf(scale, pp0, b);
      out[((size_t)1 * 18 + l) * 512 + srow] = fmaf(scale, pp1, b);
    }
  }
}

extern "C" void kernel_launch(void* const* d_in, const int* in_sizes, int n_in,
                              void* d_out, int out_size, void* d_ws, size_t ws_size,
                              hipStream_t stream) {
  const int*   x   = (const int*)d_in[0];
  const float* w0  = (const float*)d_in[1];
  const float* cw  = (const float*)d_in[2];
  const float* cb  = (const float*)d_in[3];
  const float* pa  = (const float*)d_in[4];
  const float* fcw = (const float*)d_in[5];
  const float* fcb = (const float*)d_in[6];
  float* ws = (float*)d_ws;
  float* partial = ws;                         // 7,077,888 floats
  float* zsc  = ws + PART_SZ;                  // 576
  float* zsp  = zsc + NSNAP * 64;              // 576
  float* feat = zsp + NSNAP * 64;              // 43776
  float* out  = (float*)d_out;

  (void)hipFuncSetAttribute((const void*)kA,
      hipFuncAttributeMaxDynamicSharedMemorySize, KA_LDS);

  hipLaunchKernelGGL(kZ, dim3(1), dim3(64), 0, stream, cw, cb, pa, zsc, zsp);
  hipLaunchKernelGGL(kA, dim3(NBLK_A), dim3(256), KA_LDS, stream,
                     x, w0, cw, cb, pa, partial);
  hipLaunchKernelGGL(kB, dim3(86), dim3(256), 0, stream, partial, zsc, zsp, pa, feat);
  hipLaunchKernelGGL(kC, dim3(32, 18), dim3(256), 0, stream, feat, fcw, fcb, out);
}